// Round 2
// baseline (1212.022 us; speedup 1.0000x reference)
//
#include <hip/hip_runtime.h>

#define NG 16
#define NC 4
#define BPB 8      // batch items per block
#define TSTEPS 8

// Thread layout: 1024 threads = 256 pixels x 4 output channels.
// tid = pix*4 + o ; wave (64 lanes) = one grid row y, all 4 o's.
// Weights for (pix, o): W[pix*400 + o*100 .. +99] -- 100 contiguous floats,
// kept in 25 float4 VGPRs for the whole kernel, OOB-masked at load.
// State in LDS: float4 smv[buf][c][y][x][2 slots], slot = batch quad,
// phys slot = logical ^ ((x>>2)&1) (bank swizzle). 64 KiB total.

__device__ __forceinline__ void fma8(float w, const float4& s0, const float4& s1,
                                     float4& a0, float4& a1) {
    a0.x = fmaf(w, s0.x, a0.x);
    a0.y = fmaf(w, s0.y, a0.y);
    a0.z = fmaf(w, s0.z, a0.z);
    a0.w = fmaf(w, s0.w, a0.w);
    a1.x = fmaf(w, s1.x, a1.x);
    a1.y = fmaf(w, s1.y, a1.y);
    a1.z = fmaf(w, s1.z, a1.z);
    a1.w = fmaf(w, s1.w, a1.w);
}

__device__ __forceinline__ float4 lrelu4(float4 v) {
    float4 r;
    r.x = v.x > 0.f ? v.x : 0.1f * v.x;
    r.y = v.y > 0.f ? v.y : 0.1f * v.y;
    r.z = v.z > 0.f ? v.z : 0.1f * v.z;
    r.w = v.w > 0.f ? v.w : 0.1f * v.w;
    return r;
}

__global__ __launch_bounds__(1024)
void reservoir_kernel(const float* __restrict__ X, const float* __restrict__ W,
                      float* __restrict__ out, int batch) {
    __shared__ float4 smv[2 * NC * NG * NG * 2];   // 65536 B
    float* smf = reinterpret_cast<float*>(smv);

    const int tid = threadIdx.x;
    const int pix = tid >> 2;
    const int o   = tid & 3;
    const int y = pix >> 4;
    const int x = pix & 15;
    const long itemBase = (long)blockIdx.x * BPB;

    // ---- weights -> registers, OOB (u,v) pre-masked ----
    float4 wv[25];
    {
        const float4* wp = reinterpret_cast<const float4*>(W + (size_t)pix * 400 + o * 100);
        #pragma unroll
        for (int i = 0; i < 25; ++i) wv[i] = wp[i];
        float mu[5], mv[5];
        #pragma unroll
        for (int u = 0; u < 5; ++u) mu[u] = ((unsigned)(y + u - 2) < 16u) ? 1.f : 0.f;
        #pragma unroll
        for (int v = 0; v < 5; ++v) mv[v] = ((unsigned)(x + v - 2) < 16u) ? 1.f : 0.f;
        float* wf = reinterpret_cast<float*>(wv);
        #pragma unroll
        for (int cuv = 0; cuv < 100; ++cuv) {
            const int uv = cuv % 25;          // compile-time per unrolled iter
            wf[cuv] *= mu[uv / 5] * mv[uv % 5];
        }
    }

    // ---- init: X (first 784 of 1024 slots) -> LDS buf 0 ----
    {
        const int c  = tid >> 8;
        const int rem = tid & 255;
        const int yy = rem >> 4;
        const int xx = rem & 15;
        const int sw = (xx >> 2) & 1;
        #pragma unroll
        for (int k = 0; k < BPB; ++k) {
            float v = 0.f;
            if (tid < 784 && itemBase + k < batch)
                v = X[(itemBase + k) * 784 + tid];
            const int phys = (k >> 2) ^ sw;
            smf[((c * NG + yy) * NG + xx) * 8 + phys * 4 + (k & 3)] = v;
        }
    }
    __syncthreads();

    // per-thread address pieces (float4 indices)
    int ybf[5], xbf[5];
    #pragma unroll
    for (int u = 0; u < 5; ++u) {
        int yy = y + u - 2;
        yy = yy < 0 ? 0 : (yy > 15 ? 15 : yy);
        ybf[u] = yy * (NG * 2);
    }
    #pragma unroll
    for (int v = 0; v < 5; ++v) {
        int xv = x + v - 2;
        xv = xv < 0 ? 0 : (xv > 15 ? 15 : xv);
        xbf[v] = xv * 2 + ((xv >> 2) & 1);    // phys slot-0 offset
    }
    const int swx = (x >> 2) & 1;

    #pragma unroll 1
    for (int t = 0; t < TSTEPS; ++t) {
        const int rbase = (t & 1) * (NC * NG * NG * 2);   // 2048 float4 per buffer
        float4 a0 = {0, 0, 0, 0}, a1 = {0, 0, 0, 0};

        #pragma unroll
        for (int u = 0; u < 5; ++u) {
            #pragma unroll
            for (int v = 0; v < 5; ++v) {
                const int yx0 = ybf[u] + xbf[v];   // logical slot 0 (batches 0-3)
                const int yx1 = yx0 ^ 1;           // logical slot 1 (batches 4-7)
                #pragma unroll
                for (int c = 0; c < NC; ++c) {
                    const float4 s0 = smv[rbase + c * (NG * NG * 2) + yx0];
                    const float4 s1 = smv[rbase + c * (NG * NG * 2) + yx1];
                    const int cuv = c * 25 + u * 5 + v;    // compile-time
                    const float w = reinterpret_cast<const float*>(wv)[cuv];
                    fma8(w, s0, s1, a0, a1);
                }
            }
        }

        a0 = lrelu4(a0);
        a1 = lrelu4(a1);

        if (t < TSTEPS - 1) {
            const int wbase = ((t & 1) ^ 1) * (NC * NG * NG * 2);
            const int wa = wbase + o * (NG * NG * 2) + (y * NG + x) * 2;
            smv[wa + swx]       = a0;    // logical slot 0
            smv[wa + (swx ^ 1)] = a1;    // logical slot 1
            __syncthreads();
        } else {
            // channel-mean over the 4 o-lanes of this quad
            float4 r0 = a0, r1 = a1;
            r0.x += __shfl_xor(r0.x, 1); r0.x += __shfl_xor(r0.x, 2);
            r0.y += __shfl_xor(r0.y, 1); r0.y += __shfl_xor(r0.y, 2);
            r0.z += __shfl_xor(r0.z, 1); r0.z += __shfl_xor(r0.z, 2);
            r0.w += __shfl_xor(r0.w, 1); r0.w += __shfl_xor(r0.w, 2);
            r1.x += __shfl_xor(r1.x, 1); r1.x += __shfl_xor(r1.x, 2);
            r1.y += __shfl_xor(r1.y, 1); r1.y += __shfl_xor(r1.y, 2);
            r1.z += __shfl_xor(r1.z, 1); r1.z += __shfl_xor(r1.z, 2);
            r1.w += __shfl_xor(r1.w, 1); r1.w += __shfl_xor(r1.w, 2);
            r0.x *= 0.25f; r0.y *= 0.25f; r0.z *= 0.25f; r0.w *= 0.25f;
            r1.x *= 0.25f; r1.y *= 0.25f; r1.z *= 0.25f; r1.w *= 0.25f;
            // lane o writes batch items 2o and 2o+1
            const float s0sel = (o == 0) ? r0.x : (o == 1) ? r0.z : (o == 2) ? r1.x : r1.z;
            const float s1sel = (o == 0) ? r0.y : (o == 1) ? r0.w : (o == 2) ? r1.y : r1.w;
            const long b0 = itemBase + 2 * o;
            if (b0 < batch)     out[b0 * 256 + pix]       = s0sel;
            if (b0 + 1 < batch) out[(b0 + 1) * 256 + pix] = s1sel;
        }
    }
}

extern "C" void kernel_launch(void* const* d_in, const int* in_sizes, int n_in,
                              void* d_out, int out_size, void* d_ws, size_t ws_size,
                              hipStream_t stream) {
    const float* X = (const float*)d_in[0];
    const float* W = (const float*)d_in[1];
    float* out = (float*)d_out;
    const int batch = in_sizes[0] / 784;            // 8192
    const int blocks = (batch + BPB - 1) / BPB;     // 1024

    reservoir_kernel<<<blocks, 1024, 0, stream>>>(X, W, out, batch);
}